// Round 16
// baseline (624.705 us; speedup 1.0000x reference)
//
#include <hip/hip_runtime.h>
#include <hip/hip_bf16.h>
#include <cstdint>
#include <cstddef>

typedef __bf16 bf16;
typedef __bf16 bf16x8 __attribute__((ext_vector_type(8)));
typedef float f32x4 __attribute__((ext_vector_type(4)));

#define N_PTS 131072
#define CDIM  512
#define C3    1536
#define HD    64
#define NH    8
#define KWIN  128

static __device__ __forceinline__ bf16 cvt(float x) { return (bf16)x; }

// async global->LDS, 16B per lane. LDS dest = wave-uniform base + lane*16.
static __device__ __forceinline__ void gld16(const bf16* g, bf16* l) {
    __builtin_amdgcn_global_load_lds(
        (const __attribute__((address_space(1))) void*)g,
        (__attribute__((address_space(3))) void*)l, 16, 0, 0);
}

// rotate a 128-bit value right by r 16-bit elements (r per-lane, 0..7).
static __device__ __forceinline__ uint4 rot128(uint4 u, int r) {
    uint32_t x = u.x, y = u.y, z = u.z, w = u.w;
    uint32_t x1 = (x >> 16) | (y << 16), y1 = (y >> 16) | (z << 16),
             z1 = (z >> 16) | (w << 16), w1 = (w >> 16) | (x << 16);
    bool o1 = r & 1;
    x = o1 ? x1 : x; y = o1 ? y1 : y; z = o1 ? z1 : z; w = o1 ? w1 : w;
    bool o2 = r & 2;
    uint32_t t0 = x;
    x = o2 ? y : x; y = o2 ? z : y; z = o2 ? w : z; w = o2 ? t0 : w;
    bool o4 = r & 4;
    uint32_t tx = x, ty = y;
    x = o4 ? z : x; y = o4 ? w : y; z = o4 ? tx : z; w = o4 ? ty : w;
    uint4 o; o.x = x; o.y = y; o.z = z; o.w = w; return o;
}

// ---------------------------------------------------------------------------
// Weight prep: transpose + cast f32 -> bf16.  Wt[col][k] = W[k][col].
// ---------------------------------------------------------------------------
__global__ __launch_bounds__(256) void k_prep(
    const float* __restrict__ Wqkv, const float* __restrict__ Wproj,
    bf16* __restrict__ Wqkv_t, bf16* __restrict__ Wproj_t)
{
    int idx = blockIdx.x * 256 + threadIdx.x;
    if (idx < CDIM * C3) {
        int k = idx / C3, c = idx % C3;
        Wqkv_t[(size_t)c * CDIM + k] = cvt(Wqkv[idx]);
    } else {
        int j = idx - CDIM * C3;
        if (j < CDIM * CDIM) {
            int k = j / CDIM, c = j % CDIM;
            Wproj_t[(size_t)c * CDIM + k] = cvt(Wproj[j]);
        }
    }
}

// ---------------------------------------------------------------------------
// Gather + cast: feat_g[i][:] = bf16(feat[order[i]][:])  (HBM-floor pass)
// ---------------------------------------------------------------------------
__global__ __launch_bounds__(256) void k_gather(
    const float* __restrict__ feat, const int* __restrict__ order,
    bf16* __restrict__ feat_g)
{
    int row = blockIdx.x * 2 + (threadIdx.x >> 7);
    int c   = (threadIdx.x & 127) << 2;
    int src = order[row];
    float4 v = *reinterpret_cast<const float4*>(feat + (size_t)src * CDIM + c);
    union { bf16 e[4]; uint2 u; } pk;
    pk.e[0] = cvt(v.x); pk.e[1] = cvt(v.y); pk.e[2] = cvt(v.z); pk.e[3] = cvt(v.w);
    *reinterpret_cast<uint2*>(feat_g + (size_t)row * CDIM + c) = pk.u;
}

// ---------------------------------------------------------------------------
// 8-phase GEMM for qkv (R11 exact — best measured qkv: 275us, MfmaUtil 32%):
// out = A @ Bt^T + bias, bf16 out. BM=BN=256, BK=64, 8 waves, 2-buf LDS 128KB.
// ---------------------------------------------------------------------------
template <int NT>
__global__ __launch_bounds__(512) void k_gemm8(
    const bf16* __restrict__ Ag, const bf16* __restrict__ Bt,
    const float* __restrict__ bias, bf16* __restrict__ outp)
{
    __shared__ __align__(16) bf16 As[2][256 * 64];
    __shared__ __align__(16) bf16 Bs[2][256 * 64];

    const int t    = threadIdx.x;
    const int lane = t & 63;
    const int wv   = t >> 6;
    const int wr   = wv >> 2;
    const int wc   = wv & 3;
    const int g    = lane >> 4, r16 = lane & 15;

    const int nwg = gridDim.x;
    const int bid = blockIdx.x;
    const int swz = (bid & 7) * (nwg >> 3) + (bid >> 3);
    const int m0  = (swz / NT) * 256;
    const int n0  = (swz % NT) * 256;

    const int NKT = CDIM / 64;

    int aSrc[2][2], bSrc[2][2], dstE[2][2];
#pragma unroll
    for (int h = 0; h < 2; ++h)
#pragma unroll
        for (int j = 0; j < 2; ++j) {
            int L = wv * 128 + j * 64 + lane;
            int row_l = L >> 3, p8 = L & 7;
            int s8 = (p8 - (row_l & 7)) & 7;
            int grow = h * 128 + row_l;
            aSrc[h][j] = (m0 + grow) * CDIM + s8 * 8;
            bSrc[h][j] = (n0 + grow) * CDIM + s8 * 8;
            dstE[h][j] = h * 8192 + (wv * 128 + j * 64) * 8;
        }

    int aoff[2][2][4];
    int boff[2][4];
#pragma unroll
    for (int grp = 0; grp < 2; ++grp)
#pragma unroll
        for (int kh = 0; kh < 2; ++kh)
#pragma unroll
            for (int q = 0; q < 4; ++q) {
                int row = wr * 128 + (grp * 4 + q) * 16 + r16;
                aoff[grp][kh][q] = row * 128 +
                    (((kh * 4 + g + (r16 & 7)) & 7) << 4);
            }
#pragma unroll
    for (int kh = 0; kh < 2; ++kh)
#pragma unroll
        for (int n = 0; n < 4; ++n) {
            int row = wc * 64 + n * 16 + r16;
            boff[kh][n] = row * 128 +
                (((kh * 4 + g + (r16 & 7)) & 7) << 4);
        }

    f32x4 acc[8][4];
    const f32x4 z = {0.f, 0.f, 0.f, 0.f};
#pragma unroll
    for (int i = 0; i < 8; ++i)
#pragma unroll
        for (int n = 0; n < 4; ++n) acc[i][n] = z;

    bf16x8 afr[2][4], bfr[2][4];

    auto stageA = [&](int tau) {
        const int b = tau & 1, ko = tau * 64;
#pragma unroll
        for (int h = 0; h < 2; ++h)
#pragma unroll
            for (int j = 0; j < 2; ++j)
                gld16(Ag + aSrc[h][j] + ko, &As[b][dstE[h][j]]);
    };
    auto stageB = [&](int tau) {
        const int b = tau & 1, ko = tau * 64;
#pragma unroll
        for (int h = 0; h < 2; ++h)
#pragma unroll
            for (int j = 0; j < 2; ++j)
                gld16(Bt + bSrc[h][j] + ko, &Bs[b][dstE[h][j]]);
    };
    auto readA = [&](int set, int b, int grp, int kh) {
        const char* ab = reinterpret_cast<const char*>(&As[b][0]);
#pragma unroll
        for (int q = 0; q < 4; ++q)
            afr[set][q] = *reinterpret_cast<const bf16x8*>(ab + aoff[grp][kh][q]);
    };
    auto readB = [&](int b, int kh) {
        const char* bb = reinterpret_cast<const char*>(&Bs[b][0]);
#pragma unroll
        for (int n = 0; n < 4; ++n)
            bfr[kh][n] = *reinterpret_cast<const bf16x8*>(bb + boff[kh][n]);
    };

    stageB(0); stageA(0); stageB(1); stageA(1);
    asm volatile("s_waitcnt vmcnt(8)" ::: "memory");
    __builtin_amdgcn_s_barrier();
    readA(0, 0, 0, 0);
    readB(0, 0);
    asm volatile("s_waitcnt lgkmcnt(0)" ::: "memory");
    __builtin_amdgcn_sched_barrier(0);

#pragma unroll
    for (int tau = 0; tau < NKT; ++tau) {
#pragma unroll
        for (int p = 0; p < 4; ++p) {
            const int pi  = tau * 4 + p;
            const int grp = p & 1, kh = p >> 1;

            if (p == 2 && tau + 2 < NKT) stageB(tau + 2);
            if (p == 3 && tau + 2 < NKT) stageA(tau + 2);

            if (pi + 1 < NKT * 4) {
                const int pn   = (p + 1) & 3;
                const int taun = tau + (p == 3);
                const int bn   = taun & 1;
                readA((pi + 1) & 1, bn, pn & 1, pn >> 1);
                if (pn == 0 || pn == 2) readB(bn, pn >> 1);
            }

            __builtin_amdgcn_s_setprio(1);
#pragma unroll
            for (int q = 0; q < 4; ++q)
#pragma unroll
                for (int n = 0; n < 4; ++n)
                    acc[grp * 4 + q][n] = __builtin_amdgcn_mfma_f32_16x16x32_bf16(
                        afr[pi & 1][q], bfr[kh][n], acc[grp * 4 + q][n], 0, 0, 0);
            __builtin_amdgcn_s_setprio(0);

            asm volatile("s_waitcnt lgkmcnt(0)" ::: "memory");
            __builtin_amdgcn_sched_barrier(0);
            if (p == 2) {
                if (tau + 2 < NKT)
                    asm volatile("s_waitcnt vmcnt(4)" ::: "memory");
                else
                    asm volatile("s_waitcnt vmcnt(0)" ::: "memory");
            }
            __builtin_amdgcn_s_barrier();
        }
    }

    const int ldo = NT * 256;
#pragma unroll
    for (int n = 0; n < 4; ++n) {
        int col = n0 + wc * 64 + n * 16 + r16;
        float b = bias[col];
#pragma unroll
        for (int i = 0; i < 8; ++i)
#pragma unroll
            for (int j = 0; j < 4; ++j) {
                int row = m0 + wr * 128 + i * 16 + g * 4 + j;
                outp[(size_t)row * ldo + col] = cvt(acc[i][n][j] + b);
            }
    }
}

// ---------------------------------------------------------------------------
// proj GEMM — R5/R8 structure (measured ~95-100us): 128x256 tile, BK=32,
// 8 waves, 2-deep ring, rotate-permute LDS, gld16 both operands, vmcnt(3).
// ---------------------------------------------------------------------------
template <int NT>
__global__ __launch_bounds__(512, 4) void k_proj(
    const bf16* __restrict__ Ag, const bf16* __restrict__ Bt,
    const float* __restrict__ bias, float* __restrict__ outp)
{
    __shared__ __align__(16) bf16 As[2][128 * 32];
    __shared__ __align__(16) bf16 Bs[2][256 * 32];

    const int t    = threadIdx.x;
    const int lane = t & 63;
    const int wv   = t >> 6;
    const int wr   = wv >> 2;
    const int wc   = wv & 3;
    const int g    = lane >> 4, r16 = lane & 15;

    const int nwg = gridDim.x;
    const int bid = blockIdx.x;
    const int swz = (bid & 7) * (nwg >> 3) + (bid >> 3);
    const int m0  = (swz / NT) * 128;
    const int n0  = (swz % NT) * 256;

    const int L0 = wv * 64 + lane;
    const int rA = L0 >> 2,          sA = ((L0 & 3) - (rA >> 1)) & 3;
    const int rB1 = rA + 128,        sB1v = ((L0 & 3) - (rB1 >> 1)) & 3;
    const bf16* srcA  = Ag + (size_t)(m0 + rA) * CDIM + sA * 8;
    const bf16* srcB0 = Bt + (size_t)(n0 + rA) * CDIM + sA * 8;
    const bf16* srcB1 = Bt + (size_t)(n0 + rB1) * CDIM + sB1v * 8;

    int aoff[4], boff[4];
#pragma unroll
    for (int m = 0; m < 4; ++m) {
        int row = wr * 64 + m * 16 + r16;
        aoff[m] = row * 64 + (((g + (row >> 1)) & 3) << 4);
    }
#pragma unroll
    for (int n = 0; n < 4; ++n) {
        int row = wc * 64 + n * 16 + r16;
        boff[n] = row * 64 + (((g + (row >> 1)) & 3) << 4);
    }

    f32x4 acc[4][4];
    const f32x4 z = {0.f, 0.f, 0.f, 0.f};
#pragma unroll
    for (int m = 0; m < 4; ++m)
#pragma unroll
        for (int n = 0; n < 4; ++n) acc[m][n] = z;

    auto stage = [&](int kt) {
        const int b  = kt & 1;
        const int ko = kt * 32;
        gld16(srcA  + ko, &As[b][(size_t)wv * 64 * 8]);
        gld16(srcB0 + ko, &Bs[b][(size_t)wv * 64 * 8]);
        gld16(srcB1 + ko, &Bs[b][(size_t)(512 + wv * 64) * 8]);
    };

    auto compute = [&](int kt) {
        const int b = kt & 1;
        bf16x8 af[4], bvv[4];
#pragma unroll
        for (int m = 0; m < 4; ++m)
            af[m] = *reinterpret_cast<const bf16x8*>(
                reinterpret_cast<const char*>(&As[b][0]) + aoff[m]);
#pragma unroll
        for (int n = 0; n < 4; ++n)
            bvv[n] = *reinterpret_cast<const bf16x8*>(
                reinterpret_cast<const char*>(&Bs[b][0]) + boff[n]);
        __builtin_amdgcn_s_setprio(1);
#pragma unroll
        for (int m = 0; m < 4; ++m)
#pragma unroll
            for (int n = 0; n < 4; ++n)
                acc[m][n] = __builtin_amdgcn_mfma_f32_16x16x32_bf16(
                    af[m], bvv[n], acc[m][n], 0, 0, 0);
        __builtin_amdgcn_s_setprio(0);
    };

    const int NKT = CDIM / 32;

    stage(0); stage(1);
    asm volatile("s_waitcnt vmcnt(3)" ::: "memory");
    __builtin_amdgcn_s_barrier();

#pragma unroll
    for (int kt = 0; kt < NKT - 2; ++kt) {
        compute(kt);
        asm volatile("s_waitcnt lgkmcnt(0)" ::: "memory");
        __builtin_amdgcn_s_barrier();
        stage(kt + 2);
        asm volatile("s_waitcnt vmcnt(3)" ::: "memory");
        __builtin_amdgcn_s_barrier();
    }
    compute(NKT - 2);
    asm volatile("s_waitcnt vmcnt(0) lgkmcnt(0)" ::: "memory");
    __builtin_amdgcn_s_barrier();
    compute(NKT - 1);

    const int ldo = NT * 256;
#pragma unroll
    for (int n = 0; n < 4; ++n) {
        int col = n0 + wc * 64 + n * 16 + r16;
        float b = bias[col];
#pragma unroll
        for (int m = 0; m < 4; ++m)
#pragma unroll
            for (int j = 0; j < 4; ++j) {
                int row = m0 + wr * 64 + m * 16 + g * 4 + j;
                outp[(size_t)row * ldo + col] = acc[m][n][j] + b;
            }
    }
}

// ---------------------------------------------------------------------------
// Attention (R15): one block per (window, head), 4 waves x 32 query rows.
// rot128-rotated V transpose stores (bank-conflict-free writes, 2-way reads).
// Output rows SCATTERED to attn_g[order[w*128+tok]].
// ---------------------------------------------------------------------------
__global__ __launch_bounds__(256, 2) void k_attn(
    const bf16* __restrict__ qkv_s, const int* __restrict__ order,
    bf16* __restrict__ attn_g)
{
    __shared__ __align__(16) char smem[36864 + 64 * 136 * 2];
    __shared__ int ord_s[KWIN];
    bf16 (*Q)[72]   = reinterpret_cast<bf16 (*)[72]>(smem);
    bf16 (*Kt)[72]  = reinterpret_cast<bf16 (*)[72]>(smem + 128 * 72 * 2);
    bf16 (*P)[136]  = reinterpret_cast<bf16 (*)[136]>(smem);          // overlaps Q,Kt
    bf16 (*Vt)[136] = reinterpret_cast<bf16 (*)[136]>(smem + 36864);  // V transposed
    unsigned short* Vtu = reinterpret_cast<unsigned short*>(smem + 36864);

    const int t    = threadIdx.x;
    const int lane = t & 63;
    const int wv   = t >> 6;
    const int g    = lane >> 4, r16 = lane & 15;
    const int h    = blockIdx.x;
    const int w    = blockIdx.y;

    const bf16* base = qkv_s + (size_t)w * KWIN * C3 + h * HD;

    if (t < KWIN) ord_s[t] = order[w * KWIN + t];

    const int rot = t & 7;

#pragma unroll
    for (int it = 0; it < 4; ++it) {
        int s   = it * 256 + t;
        int tok = s >> 3;
        int c8  = (s & 7) << 3;
        size_t roff = (size_t)tok * C3 + c8;
        *reinterpret_cast<uint4*>(&Q[tok][c8])  =
            *reinterpret_cast<const uint4*>(base + roff);
        *reinterpret_cast<uint4*>(&Kt[tok][c8]) =
            *reinterpret_cast<const uint4*>(base + roff + CDIM);
        uint4 vvec = *reinterpret_cast<const uint4*>(base + roff + 2 * CDIM);
        uint4 vr = rot128(vvec, rot);
        uint32_t wd[4] = {vr.x, vr.y, vr.z, vr.w};
#pragma unroll
        for (int k = 0; k < 8; ++k) {
            int d = c8 + ((k + rot) & 7);
            Vtu[d * 136 + tok] =
                (unsigned short)(wd[k >> 1] >> ((k & 1) * 16));
        }
    }
    __syncthreads();

    f32x4 sc[2][8];
    const f32x4 z = {0.f, 0.f, 0.f, 0.f};
#pragma unroll
    for (int m = 0; m < 2; ++m)
#pragma unroll
        for (int n = 0; n < 8; ++n) sc[m][n] = z;

#pragma unroll
    for (int ks = 0; ks < 2; ++ks) {
        bf16x8 aq[2];
#pragma unroll
        for (int m = 0; m < 2; ++m)
            aq[m] = *reinterpret_cast<const bf16x8*>(
                &Q[wv * 32 + m * 16 + r16][ks * 32 + g * 8]);
#pragma unroll
        for (int n = 0; n < 8; ++n) {
            bf16x8 bk = *reinterpret_cast<const bf16x8*>(
                &Kt[n * 16 + r16][ks * 32 + g * 8]);
#pragma unroll
            for (int m = 0; m < 2; ++m)
                sc[m][n] = __builtin_amdgcn_mfma_f32_16x16x32_bf16(
                    aq[m], bk, sc[m][n], 0, 0, 0);
        }
    }

    const float scale = 0.125f;   // hd^-0.5
    float inv_sum[2][4];
#pragma unroll
    for (int m = 0; m < 2; ++m) {
#pragma unroll
        for (int j = 0; j < 4; ++j) {
            float mx = -3.0e38f;
#pragma unroll
            for (int n = 0; n < 8; ++n) mx = fmaxf(mx, sc[m][n][j]);
            mx = fmaxf(mx, __shfl_xor(mx, 1));
            mx = fmaxf(mx, __shfl_xor(mx, 2));
            mx = fmaxf(mx, __shfl_xor(mx, 4));
            mx = fmaxf(mx, __shfl_xor(mx, 8));
            mx *= scale;
            float ssum = 0.f;
#pragma unroll
            for (int n = 0; n < 8; ++n) {
                float p = __expf(sc[m][n][j] * scale - mx);
                sc[m][n][j] = p;
                ssum += p;
            }
            ssum += __shfl_xor(ssum, 1);
            ssum += __shfl_xor(ssum, 2);
            ssum += __shfl_xor(ssum, 4);
            ssum += __shfl_xor(ssum, 8);
            inv_sum[m][j] = 1.f / ssum;
        }
    }

    __syncthreads();   // all waves done reading Q/Kt before P overwrites them

#pragma unroll
    for (int m = 0; m < 2; ++m)
#pragma unroll
        for (int n = 0; n < 8; ++n)
#pragma unroll
            for (int j = 0; j < 4; ++j)
                P[wv * 32 + m * 16 + g * 4 + j][n * 16 + r16] =
                    cvt(sc[m][n][j] * inv_sum[m][j]);

    f32x4 o[2][4];
#pragma unroll
    for (int m = 0; m < 2; ++m)
#pragma unroll
        for (int n = 0; n < 4; ++n) o[m][n] = z;

#pragma unroll
    for (int kt = 0; kt < 4; ++kt) {
        bf16x8 ap[2];
#pragma unroll
        for (int m = 0; m < 2; ++m)
            ap[m] = *reinterpret_cast<const bf16x8*>(
                &P[wv * 32 + m * 16 + r16][kt * 32 + g * 8]);
#pragma unroll
        for (int n = 0; n < 4; ++n) {
            bf16x8 bvv = *reinterpret_cast<const bf16x8*>(
                &Vt[n * 16 + r16][kt * 32 + g * 8]);
#pragma unroll
            for (int m = 0; m < 2; ++m)
                o[m][n] = __builtin_amdgcn_mfma_f32_16x16x32_bf16(
                    ap[m], bvv, o[m][n], 0, 0, 0);
        }
    }

#pragma unroll
    for (int m = 0; m < 2; ++m)
#pragma unroll
        for (int n = 0; n < 4; ++n)
#pragma unroll
            for (int j = 0; j < 4; ++j) {
                int tok  = wv * 32 + m * 16 + g * 4 + j;
                int d    = n * 16 + r16;
                int drow = ord_s[tok];
                attn_g[(size_t)drow * CDIM + h * HD + d] = cvt(o[m][n][j]);
            }
}

// ---------------------------------------------------------------------------
extern "C" void kernel_launch(void* const* d_in, const int* in_sizes, int n_in,
                              void* d_out, int out_size, void* d_ws, size_t ws_size,
                              hipStream_t stream)
{
    const float* feat    = (const float*)d_in[0];
    const float* Wqkv    = (const float*)d_in[1];
    const float* bqkv    = (const float*)d_in[2];
    const float* Wproj   = (const float*)d_in[3];
    const float* bproj   = (const float*)d_in[4];
    const int*   order   = (const int*)d_in[5];
    float* out = (float*)d_out;

    const size_t qkv_bytes = (size_t)N_PTS * C3 * sizeof(bf16);    // 402.7 MB
    const size_t gat_bytes = (size_t)N_PTS * CDIM * sizeof(bf16);  // 134.2 MB
    const size_t wq_bytes  = (size_t)C3 * CDIM * sizeof(bf16);
    const size_t wp_bytes  = (size_t)CDIM * CDIM * sizeof(bf16);
    if (ws_size < qkv_bytes + gat_bytes + wq_bytes + wp_bytes) return;

    bf16* qkv_s     = (bf16*)d_ws;
    bf16* shared134 = (bf16*)((char*)d_ws + qkv_bytes);   // feat_g, later attn_g
    bf16* Wqkv_t    = (bf16*)((char*)d_ws + qkv_bytes + gat_bytes);
    bf16* Wproj_t   = (bf16*)((char*)d_ws + qkv_bytes + gat_bytes + wq_bytes);

    k_prep<<<dim3((CDIM * C3 + CDIM * CDIM + 255) / 256), 256, 0, stream>>>(
        Wqkv, Wproj, Wqkv_t, Wproj_t);
    k_gather<<<dim3(N_PTS / 2), 256, 0, stream>>>(feat, order, shared134);
    // qkv GEMM: [131072 x 1536] = feat_g @ Wqkv_t^T  (512 x 6 = 3072 blocks)
    k_gemm8<C3 / 256><<<dim3((N_PTS / 256) * (C3 / 256)), 512, 0, stream>>>(
        shared134, Wqkv_t, bqkv, qkv_s);
    // attention (reads qkv_s, scatters into shared134 = attn_g)
    k_attn<<<dim3(NH, N_PTS / KWIN), 256, 0, stream>>>(qkv_s, order, shared134);
    // proj GEMM: [131072 x 512] = attn_g @ Wproj_t^T  (1024 x 2 = 2048 blocks)
    k_proj<CDIM / 256><<<dim3((N_PTS / 128) * (CDIM / 256)), 512, 0, stream>>>(
        shared134, Wproj_t, bproj, out);
}